// Round 1
// baseline (1506.727 us; speedup 1.0000x reference)
//
#include <hip/hip_runtime.h>
#include <math.h>

#define B_ 64
#define L_ 2048
#define C_ 512
#define R_ 64
#define TL 16

// ---------------------------------------------------------------------------
// Kernel T: WdT[l][r] = Wd[r][l]   (R_ x L_) -> (L_ x R_)
// Coalesced read of Wd, scattered write (only 512 KB, negligible).
// ---------------------------------------------------------------------------
__global__ void k_transpose_wd(const float* __restrict__ Wd,
                               float* __restrict__ WdT) {
    int i = blockIdx.x * blockDim.x + threadIdx.x;   // over R_*L_
    if (i < R_ * L_) {
        int r = i / L_;
        int l = i - r * L_;
        WdT[l * R_ + r] = Wd[i];
    }
}

// ---------------------------------------------------------------------------
// Kernel A: h_lowT[b][r][c] = sum_l x[b][l][c] * Wd[r][l] + bd[r]
// Block = 256 thr = 4 waves; each wave: same 64 c's, 1/4 of the l range.
// Lanes = c -> coalesced x loads. Weight row WdT[l][:] is wave-uniform ->
// scalar (s_load_dwordx4) loads. Partial sums combined through LDS.
// ---------------------------------------------------------------------------
__global__ __launch_bounds__(256) void k_hlow(const float* __restrict__ x,
                                              const float* __restrict__ WdT,
                                              const float* __restrict__ bd,
                                              float* __restrict__ hlT) {
    const int lane = threadIdx.x & 63;
    const int wv   = threadIdx.x >> 6;              // 0..3
    const int c    = blockIdx.x * 64 + lane;
    const int b    = blockIdx.y;

    float acc[R_];
#pragma unroll
    for (int r = 0; r < R_; ++r) acc[r] = 0.f;

    const float* xp = x + (size_t)b * L_ * C_ + c;
    const int l0 = wv * (L_ / 4);
    const int l1 = l0 + (L_ / 4);
    for (int l = l0; l < l1; ++l) {
        float xv = xp[(size_t)l * C_];
        const float4* w4 = reinterpret_cast<const float4*>(WdT + l * R_);
#pragma unroll
        for (int i = 0; i < R_ / 4; ++i) {
            float4 w = w4[i];
            acc[4 * i + 0] += xv * w.x;
            acc[4 * i + 1] += xv * w.y;
            acc[4 * i + 2] += xv * w.z;
            acc[4 * i + 3] += xv * w.w;
        }
    }

    // combine 4 waves' partials. stride 65 -> bank = (lane + r) % 32, conflict-free
    __shared__ float red[3][64][R_ + 1];
    if (wv > 0) {
#pragma unroll
        for (int r = 0; r < R_; ++r) red[wv - 1][lane][r] = acc[r];
    }
    __syncthreads();
    if (wv == 0) {
#pragma unroll
        for (int r = 0; r < R_; ++r) {
            float t = acc[r] + red[0][lane][r] + red[1][lane][r] + red[2][lane][r];
            hlT[((size_t)b * R_ + r) * C_ + c] = t + bd[r];
        }
    }
}

// ---------------------------------------------------------------------------
// Kernel B: per (b,c):
//   q_s = h . Wq[s,:], k_s = h . Wk[s,:]  (pass 1: norms)
//   pass 2: recompute q,k + v,g; P = (q/|q|)*sigmoid(g+bg); store PT[b][s][c]
//   G[b][s] += sum_c (k/|k|)*v   (wave butterfly reduce + 1 atomic/lane0)
// One wave per block; h row in 64 VGPRs; weight rows are uniform -> s_loads.
// ---------------------------------------------------------------------------
__global__ __launch_bounds__(64) void k_qkvg(const float* __restrict__ hlT,
                                             const float* __restrict__ Wq,
                                             const float* __restrict__ Wk,
                                             const float* __restrict__ Wv,
                                             const float* __restrict__ Wg,
                                             const float* __restrict__ bg,
                                             float* __restrict__ PT,
                                             float* __restrict__ G) {
    const int c = blockIdx.x * 64 + threadIdx.x;
    const int b = blockIdx.y;

    float h[R_];
#pragma unroll
    for (int r = 0; r < R_; ++r) h[r] = hlT[((size_t)b * R_ + r) * C_ + c];

    float sq = 0.f, sk = 0.f;
    for (int s = 0; s < R_; ++s) {
        float q = 0.f, k = 0.f;
        const float4* wq4 = reinterpret_cast<const float4*>(Wq + s * R_);
        const float4* wk4 = reinterpret_cast<const float4*>(Wk + s * R_);
#pragma unroll
        for (int i = 0; i < R_ / 4; ++i) {
            float4 a = wq4[i];
            float4 d = wk4[i];
            q += h[4 * i] * a.x + h[4 * i + 1] * a.y + h[4 * i + 2] * a.z + h[4 * i + 3] * a.w;
            k += h[4 * i] * d.x + h[4 * i + 1] * d.y + h[4 * i + 2] * d.z + h[4 * i + 3] * d.w;
        }
        sq += q * q;
        sk += k * k;
    }
    const float inq = 1.f / fmaxf(sqrtf(sq), 1e-12f);
    const float ink = 1.f / fmaxf(sqrtf(sk), 1e-12f);

    for (int s = 0; s < R_; ++s) {
        float q = 0.f, k = 0.f, v = 0.f, g = 0.f;
        const float4* wq4 = reinterpret_cast<const float4*>(Wq + s * R_);
        const float4* wk4 = reinterpret_cast<const float4*>(Wk + s * R_);
        const float4* wv4 = reinterpret_cast<const float4*>(Wv + s * R_);
        const float4* wg4 = reinterpret_cast<const float4*>(Wg + s * R_);
#pragma unroll
        for (int i = 0; i < R_ / 4; ++i) {
            float4 a = wq4[i], d = wk4[i], e = wv4[i], f = wg4[i];
            float h0 = h[4 * i], h1 = h[4 * i + 1], h2 = h[4 * i + 2], h3 = h[4 * i + 3];
            q += h0 * a.x + h1 * a.y + h2 * a.z + h3 * a.w;
            k += h0 * d.x + h1 * d.y + h2 * d.z + h3 * d.w;
            v += h0 * e.x + h1 * e.y + h2 * e.z + h3 * e.w;
            g += h0 * f.x + h1 * f.y + h2 * f.z + h3 * f.w;
        }
        g = 1.f / (1.f + expf(-(g + bg[s])));
        PT[((size_t)b * R_ + s) * C_ + c] = q * inq * g;

        float kv = (k * ink) * v;
#pragma unroll
        for (int off = 32; off > 0; off >>= 1) kv += __shfl_xor(kv, off, 64);
        if (threadIdx.x == 0) atomicAdd(&G[b * R_ + s], kv);
    }
}

// ---------------------------------------------------------------------------
// Kernel C: out[b][l][c] = LN_c( x[b][l][c] + alpha*(sum_r PT[b][r][c]*G[b][r]
//                                 *Wu[l][r] + bu[l]) ) * gamma[c] + beta[c]
// Block = 512 thr (= all c) x TL l's. h_attn row in registers; Wu rows
// uniform -> scalar loads. LN: 64-lane butterfly + LDS cross-wave combine.
// ---------------------------------------------------------------------------
__global__ __launch_bounds__(512) void k_out(const float* __restrict__ x,
                                             const float* __restrict__ PT,
                                             const float* __restrict__ G,
                                             const float* __restrict__ Wu,
                                             const float* __restrict__ bu,
                                             const float* __restrict__ gamma,
                                             const float* __restrict__ beta,
                                             const float* __restrict__ alpha_p,
                                             float* __restrict__ out) {
    const int c  = threadIdx.x;          // 0..511
    const int b  = blockIdx.y;
    const int l0 = blockIdx.x * TL;
    const float alpha = alpha_p[0];

    float ha[R_];
#pragma unroll
    for (int r = 0; r < R_; ++r)
        ha[r] = PT[((size_t)b * R_ + r) * C_ + c] * G[b * R_ + r];

    float vals[TL];
#pragma unroll
    for (int lt = 0; lt < TL; ++lt) {
        const int l = l0 + lt;
        const float4* wu4 = reinterpret_cast<const float4*>(Wu + l * R_);
        float m = 0.f;
#pragma unroll
        for (int i = 0; i < R_ / 4; ++i) {
            float4 w = wu4[i];
            m += ha[4 * i] * w.x + ha[4 * i + 1] * w.y + ha[4 * i + 2] * w.z + ha[4 * i + 3] * w.w;
        }
        vals[lt] = x[((size_t)b * L_ + l) * C_ + c] + alpha * (m + bu[l]);
    }

    __shared__ float2 redLds[TL][8];
    __shared__ float2 mvLds[TL];
    const int lane = c & 63, wv = c >> 6;
#pragma unroll
    for (int lt = 0; lt < TL; ++lt) {
        float s = vals[lt], s2 = vals[lt] * vals[lt];
#pragma unroll
        for (int off = 32; off > 0; off >>= 1) {
            s  += __shfl_xor(s, off, 64);
            s2 += __shfl_xor(s2, off, 64);
        }
        if (lane == 0) redLds[lt][wv] = make_float2(s, s2);
    }
    __syncthreads();
    if (threadIdx.x < TL) {
        float s = 0.f, s2 = 0.f;
#pragma unroll
        for (int w = 0; w < 8; ++w) {
            s  += redLds[threadIdx.x][w].x;
            s2 += redLds[threadIdx.x][w].y;
        }
        const float mean = s * (1.f / C_);
        const float var  = s2 * (1.f / C_) - mean * mean;
        mvLds[threadIdx.x] = make_float2(mean, rsqrtf(var + 1e-5f));
    }
    __syncthreads();
    const float gm = gamma[c], bt = beta[c];
#pragma unroll
    for (int lt = 0; lt < TL; ++lt) {
        float2 mv = mvLds[lt];
        out[((size_t)b * L_ + (l0 + lt)) * C_ + c] = (vals[lt] - mv.x) * mv.y * gm + bt;
    }
}

// ---------------------------------------------------------------------------
extern "C" void kernel_launch(void* const* d_in, const int* in_sizes, int n_in,
                              void* d_out, int out_size, void* d_ws, size_t ws_size,
                              hipStream_t stream) {
    const float* x     = (const float*)d_in[0];
    const float* Wd    = (const float*)d_in[1];
    const float* bd    = (const float*)d_in[2];
    const float* Wq    = (const float*)d_in[3];
    const float* Wk    = (const float*)d_in[4];
    const float* Wv    = (const float*)d_in[5];
    const float* Wg    = (const float*)d_in[6];
    const float* bg    = (const float*)d_in[7];
    const float* Wu    = (const float*)d_in[8];
    const float* bu    = (const float*)d_in[9];
    const float* gamma = (const float*)d_in[10];
    const float* beta  = (const float*)d_in[11];
    const float* alpha = (const float*)d_in[12];
    float* out = (float*)d_out;

    char* ws = (char*)d_ws;
    float* WdT = (float*)ws;                                   // 512 KB
    float* hlT = (float*)(ws + (512 << 10));                   // 8 MB  (B,R,C)
    float* PT  = (float*)(ws + (512 << 10) + (8 << 20));       // 8 MB  (B,R,C)
    float* G   = (float*)(ws + (512 << 10) + (16 << 20));      // 16 KB (B,R)

    k_transpose_wd<<<dim3((R_ * L_) / 256), 256, 0, stream>>>(Wd, WdT);
    k_hlow<<<dim3(C_ / 64, B_), 256, 0, stream>>>(x, WdT, bd, hlT);
    hipMemsetAsync(G, 0, B_ * R_ * sizeof(float), stream);
    k_qkvg<<<dim3(C_ / 64, B_), 64, 0, stream>>>(hlT, Wq, Wk, Wv, Wg, bg, PT, G);
    k_out<<<dim3(L_ / TL, B_), 512, 0, stream>>>(x, PT, G, Wu, bu, gamma, beta, alpha, out);
}

// Round 2
// 808.219 us; speedup vs baseline: 1.8643x; 1.8643x over previous
//
#include <hip/hip_runtime.h>
#include <hip/hip_bf16.h>
#include <math.h>

#define B_ 64
#define L_ 2048
#define C_ 512
#define R_ 64
#define TL 16

#define BM 128     // c-tile per block (4 waves x 32 c)
#define BK 32      // l-chunk (one MFMA K)
#define LDK 36     // padded LDS row length in floats (144 B, 16B-aligned rows)

typedef __attribute__((ext_vector_type(8))) short bf16x8;  // 8 bf16 (4 VGPRs)
typedef __attribute__((ext_vector_type(4))) float f32x4;   // MFMA acc

static __device__ __forceinline__ unsigned pkbf(float a, float b) {
    __hip_bfloat162 t = __float22bfloat162_rn(make_float2(a, b));
    union { __hip_bfloat162 h; unsigned u; } cv;
    cv.h = t;
    return cv.u;
}

// ---------------------------------------------------------------------------
// Cast Wd (R_,L_) fp32 -> bf16, same layout. (R_,L_) row-major IS the B^T
// layout the MFMA B-fragments want (row r, contiguous l).
// ---------------------------------------------------------------------------
__global__ void k_cast_wd(const float* __restrict__ Wd,
                          __hip_bfloat16* __restrict__ Wt) {
    int i = blockIdx.x * 256 + threadIdx.x;   // grid sized exactly R_*L_/256
    Wt[i] = __float2bfloat16(Wd[i]);
}

// ---------------------------------------------------------------------------
// Kernel A (MFMA): hlT[b][r][c] += sum_l x[b][l][c] * Wd[r][l]
// Block: 256 thr = 4 waves, c-tile BM=128 (wave w owns c in [w*32,w*32+32)).
// Grid (C_/BM, 2 K-slices, B_) = 512 blocks. K-slice partial sums combined
// via global fp32 atomicAdd into zero-initialized hlT. Bias bd added later
// in k_qkvg.
// LDS: xs[c][l] fp32 (transposed tile) so A-frags read 8 consecutive l via
// two aligned float4s, converted to bf16 at frag assembly.
// ---------------------------------------------------------------------------
__global__ __launch_bounds__(256) void k_hlow_mfma(
        const float* __restrict__ x,
        const __hip_bfloat16* __restrict__ Wt,
        float* __restrict__ hlT) {
    __shared__ float xs[BM][LDK];            // 18432 B

    const int tid  = threadIdx.x;
    const int lane = tid & 63;
    const int wv   = tid >> 6;               // 0..3
    const int quad = lane >> 4;              // 0..3 -> k-offset quad*8
    const int mrow = lane & 15;

    const int c0     = blockIdx.x * BM;
    const int l_base = blockIdx.y * (L_ / 2);
    const int b      = blockIdx.z;

    // staging ownership: thread owns column c=cs, 16 l's starting at lh
    const int cs = tid & 127;
    const int lh = (tid >> 7) * 16;          // 0 or 16

    f32x4 acc[2][4];
#pragma unroll
    for (int mt = 0; mt < 2; ++mt)
#pragma unroll
        for (int nt = 0; nt < 4; ++nt)
#pragma unroll
            for (int e = 0; e < 4; ++e) acc[mt][nt][e] = 0.f;

    const float* xptr = x + ((size_t)b * L_ + l_base + lh) * C_ + c0 + cs;
    const __hip_bfloat16* wbase = Wt + l_base + quad * 8;

    for (int kc = 0; kc < L_ / 2; kc += BK) {
        // ---- global loads for this chunk (before barrier: overlap w/ MFMA)
        float v[16];
#pragma unroll
        for (int i = 0; i < 16; ++i) v[i] = xptr[(size_t)(kc + i) * C_];

        bf16x8 bfr[4];
#pragma unroll
        for (int nt = 0; nt < 4; ++nt)
            bfr[nt] = *reinterpret_cast<const bf16x8*>(
                wbase + (size_t)(nt * 16 + mrow) * L_ + kc);

        __syncthreads();                      // xs free to overwrite
#pragma unroll
        for (int i = 0; i < 16; i += 4)
            *reinterpret_cast<float4*>(&xs[cs][lh + i]) =
                make_float4(v[i], v[i + 1], v[i + 2], v[i + 3]);
        __syncthreads();                      // xs ready

        // ---- A-frags (fp32 LDS -> bf16) + MFMA
#pragma unroll
        for (int mt = 0; mt < 2; ++mt) {
            const float* ap = &xs[wv * 32 + mt * 16 + mrow][quad * 8];
            float4 lo = *reinterpret_cast<const float4*>(ap);
            float4 hi = *reinterpret_cast<const float4*>(ap + 4);
            union { bf16x8 v8; unsigned u[4]; } af;
            af.u[0] = pkbf(lo.x, lo.y);
            af.u[1] = pkbf(lo.z, lo.w);
            af.u[2] = pkbf(hi.x, hi.y);
            af.u[3] = pkbf(hi.z, hi.w);
#pragma unroll
            for (int nt = 0; nt < 4; ++nt)
                acc[mt][nt] = __builtin_amdgcn_mfma_f32_16x16x32_bf16(
                    af.v8, bfr[nt], acc[mt][nt], 0, 0, 0);
        }
    }

    // ---- epilogue: C/D layout col(n=r)=lane&15, row(m=c)=quad*4+reg
#pragma unroll
    for (int mt = 0; mt < 2; ++mt)
#pragma unroll
        for (int nt = 0; nt < 4; ++nt) {
            const int rg = nt * 16 + mrow;
            const int cg = c0 + wv * 32 + mt * 16 + quad * 4;
#pragma unroll
            for (int e = 0; e < 4; ++e)
                atomicAdd(&hlT[((size_t)b * R_ + rg) * C_ + cg + e],
                          acc[mt][nt][e]);
        }
}

// ---------------------------------------------------------------------------
// Kernel B: per (b,c): Q/K norms, P = (q/|q|)*sigmoid(g+bg), G += (k/|k|)*v.
// Block 256 thr = 4 waves over the SAME 64 c's; wave w owns s in [16w,16w+16).
// Cross-wave LDS reduce for sq/sk. h row (+bd) held in VGPRs.
// ---------------------------------------------------------------------------
__global__ __launch_bounds__(256) void k_qkvg(
        const float* __restrict__ hlT,
        const float* __restrict__ bd,
        const float* __restrict__ Wq,
        const float* __restrict__ Wk,
        const float* __restrict__ Wv,
        const float* __restrict__ Wg,
        const float* __restrict__ bg,
        float* __restrict__ PT,
        float* __restrict__ G) {
    const int lane = threadIdx.x & 63;
    const int wv   = threadIdx.x >> 6;       // s-quarter
    const int c    = blockIdx.x * 64 + lane;
    const int b    = blockIdx.y;

    float h[R_];
#pragma unroll
    for (int r = 0; r < R_; ++r)
        h[r] = hlT[((size_t)b * R_ + r) * C_ + c] + bd[r];

    // pass 1: partial sums of q^2, k^2 over this wave's 16 s-rows
    float sq = 0.f, sk = 0.f;
#pragma unroll 4
    for (int i = 0; i < 16; ++i) {
        const int s = wv * 16 + i;
        const float4* wq4 = reinterpret_cast<const float4*>(Wq + s * R_);
        const float4* wk4 = reinterpret_cast<const float4*>(Wk + s * R_);
        float q = 0.f, k = 0.f;
#pragma unroll
        for (int j = 0; j < R_ / 4; ++j) {
            float4 a = wq4[j], d = wk4[j];
            float h0 = h[4 * j], h1 = h[4 * j + 1], h2 = h[4 * j + 2], h3 = h[4 * j + 3];
            q += h0 * a.x + h1 * a.y + h2 * a.z + h3 * a.w;
            k += h0 * d.x + h1 * d.y + h2 * d.z + h3 * d.w;
        }
        sq += q * q;
        sk += k * k;
    }

    __shared__ float rq[4][64], rk[4][64];
    rq[wv][lane] = sq;
    rk[wv][lane] = sk;
    __syncthreads();
    sq = rq[0][lane] + rq[1][lane] + rq[2][lane] + rq[3][lane];
    sk = rk[0][lane] + rk[1][lane] + rk[2][lane] + rk[3][lane];
    const float inq = 1.f / fmaxf(sqrtf(sq), 1e-12f);
    const float ink = 1.f / fmaxf(sqrtf(sk), 1e-12f);

    // pass 2: P store + global-feat contribution
#pragma unroll 2
    for (int i = 0; i < 16; ++i) {
        const int s = wv * 16 + i;
        const float4* wq4 = reinterpret_cast<const float4*>(Wq + s * R_);
        const float4* wk4 = reinterpret_cast<const float4*>(Wk + s * R_);
        const float4* wv4 = reinterpret_cast<const float4*>(Wv + s * R_);
        const float4* wg4 = reinterpret_cast<const float4*>(Wg + s * R_);
        float q = 0.f, k = 0.f, v = 0.f, g = 0.f;
#pragma unroll
        for (int j = 0; j < R_ / 4; ++j) {
            float4 a = wq4[j], d = wk4[j], e = wv4[j], f = wg4[j];
            float h0 = h[4 * j], h1 = h[4 * j + 1], h2 = h[4 * j + 2], h3 = h[4 * j + 3];
            q += h0 * a.x + h1 * a.y + h2 * a.z + h3 * a.w;
            k += h0 * d.x + h1 * d.y + h2 * d.z + h3 * d.w;
            v += h0 * e.x + h1 * e.y + h2 * e.z + h3 * e.w;
            g += h0 * f.x + h1 * f.y + h2 * f.z + h3 * f.w;
        }
        const float gate = 1.f / (1.f + expf(-(g + bg[s])));
        PT[((size_t)b * R_ + s) * C_ + c] = q * inq * gate;

        float kv = (k * ink) * v;
#pragma unroll
        for (int off = 32; off > 0; off >>= 1) kv += __shfl_xor(kv, off, 64);
        if (lane == 0) atomicAdd(&G[b * R_ + s], kv);
    }
}

// ---------------------------------------------------------------------------
// Kernel C: out = LN_c( x + alpha*(PT^T G-weighted @ Wu^T + bu) )*gamma + beta
// ---------------------------------------------------------------------------
__global__ __launch_bounds__(512) void k_out(const float* __restrict__ x,
                                             const float* __restrict__ PT,
                                             const float* __restrict__ G,
                                             const float* __restrict__ Wu,
                                             const float* __restrict__ bu,
                                             const float* __restrict__ gamma,
                                             const float* __restrict__ beta,
                                             const float* __restrict__ alpha_p,
                                             float* __restrict__ out) {
    const int c  = threadIdx.x;          // 0..511
    const int b  = blockIdx.y;
    const int l0 = blockIdx.x * TL;
    const float alpha = alpha_p[0];

    float ha[R_];
#pragma unroll
    for (int r = 0; r < R_; ++r)
        ha[r] = PT[((size_t)b * R_ + r) * C_ + c] * G[b * R_ + r];

    float vals[TL];
#pragma unroll
    for (int lt = 0; lt < TL; ++lt) {
        const int l = l0 + lt;
        const float4* wu4 = reinterpret_cast<const float4*>(Wu + l * R_);
        float m = 0.f;
#pragma unroll
        for (int i = 0; i < R_ / 4; ++i) {
            float4 w = wu4[i];
            m += ha[4 * i] * w.x + ha[4 * i + 1] * w.y + ha[4 * i + 2] * w.z + ha[4 * i + 3] * w.w;
        }
        vals[lt] = x[((size_t)b * L_ + l) * C_ + c] + alpha * (m + bu[l]);
    }

    __shared__ float2 redLds[TL][8];
    __shared__ float2 mvLds[TL];
    const int lane = c & 63, wv = c >> 6;
#pragma unroll
    for (int lt = 0; lt < TL; ++lt) {
        float s = vals[lt], s2 = vals[lt] * vals[lt];
#pragma unroll
        for (int off = 32; off > 0; off >>= 1) {
            s  += __shfl_xor(s, off, 64);
            s2 += __shfl_xor(s2, off, 64);
        }
        if (lane == 0) redLds[lt][wv] = make_float2(s, s2);
    }
    __syncthreads();
    if (threadIdx.x < TL) {
        float s = 0.f, s2 = 0.f;
#pragma unroll
        for (int w = 0; w < 8; ++w) {
            s  += redLds[threadIdx.x][w].x;
            s2 += redLds[threadIdx.x][w].y;
        }
        const float mean = s * (1.f / C_);
        const float var  = s2 * (1.f / C_) - mean * mean;
        mvLds[threadIdx.x] = make_float2(mean, rsqrtf(var + 1e-5f));
    }
    __syncthreads();
    const float gm = gamma[c], bt = beta[c];
#pragma unroll
    for (int lt = 0; lt < TL; ++lt) {
        float2 mv = mvLds[lt];
        out[((size_t)b * L_ + (l0 + lt)) * C_ + c] = (vals[lt] - mv.x) * mv.y * gm + bt;
    }
}

// ---------------------------------------------------------------------------
extern "C" void kernel_launch(void* const* d_in, const int* in_sizes, int n_in,
                              void* d_out, int out_size, void* d_ws, size_t ws_size,
                              hipStream_t stream) {
    const float* x     = (const float*)d_in[0];
    const float* Wd    = (const float*)d_in[1];
    const float* bd    = (const float*)d_in[2];
    const float* Wq    = (const float*)d_in[3];
    const float* Wk    = (const float*)d_in[4];
    const float* Wv    = (const float*)d_in[5];
    const float* Wg    = (const float*)d_in[6];
    const float* bg    = (const float*)d_in[7];
    const float* Wu    = (const float*)d_in[8];
    const float* bu    = (const float*)d_in[9];
    const float* gamma = (const float*)d_in[10];
    const float* beta  = (const float*)d_in[11];
    const float* alpha = (const float*)d_in[12];
    float* out = (float*)d_out;

    char* ws = (char*)d_ws;
    __hip_bfloat16* Wt = (__hip_bfloat16*)ws;                  // 256 KB
    float* hlT = (float*)(ws + (512 << 10));                   // 8 MB  (B,R,C)
    float* PT  = (float*)(ws + (512 << 10) + (8 << 20));       // 8 MB  (B,R,C)
    float* G   = (float*)(ws + (512 << 10) + (16 << 20));      // 16 KB (B,R)

    k_cast_wd<<<dim3((R_ * L_) / 256), 256, 0, stream>>>(Wd, Wt);
    hipMemsetAsync(hlT, 0, (size_t)B_ * R_ * C_ * sizeof(float), stream);
    hipMemsetAsync(G, 0, B_ * R_ * sizeof(float), stream);
    k_hlow_mfma<<<dim3(C_ / BM, 2, B_), 256, 0, stream>>>(x, Wt, hlT);
    k_qkvg<<<dim3(C_ / 64, B_), 256, 0, stream>>>(hlT, bd, Wq, Wk, Wv, Wg, bg, PT, G);
    k_out<<<dim3(L_ / TL, B_), 512, 0, stream>>>(x, PT, G, Wu, bu, gamma, beta, alpha, out);
}